// Round 3
// baseline (7069867.188 us; speedup 1.0000x reference)
//
#include <hip/hip_runtime.h>

typedef float f32x4 __attribute__((ext_vector_type(4)));
typedef short bf16x8 __attribute__((ext_vector_type(8)));
typedef unsigned short u16;
typedef unsigned int u32;
typedef unsigned long long u64;

// ---------------- problem constants ----------------
// B=128 T=256 L=16 NW=50000 DW=300 NC=100(+1) DC=100 HC=100 H=300 NT=3
// rows = B*T = 32768 words.
// char LSTM: K padded 128 (4 kq), Hc padded 128 (8 tiles of 16)
// word LSTM: K padded 320 (10 kq), H padded 320 (20 tiles of 16)
// word-x GEMM: M=32768, K=512 (500 pad), N=2432 (2*1200 pad)

// ---------------- ws layout ----------------
#define OFF_TABLE 0ull                 // bf16 [2][101][512]
#define SZ_TABLE  206848ull
#define OFF_PACKC 206848ull            // bf16 [2][8tau][4g][4kq][64][8]
#define SZ_PACKC  262144ull
#define OFF_PACKW 468992ull            // bf16 [2][20tau][4g][10kq][64][8]
#define SZ_PACKW  1638400ull
#define OFF_BT    2107392ull           // bf16 Bt[2432][512]
#define SZ_BT     2490368ull
#define OFF_BIAS  4597760ull           // f32 [2432]
#define SZ_BIAS   9728ull
#define OFF_AW    4607488ull           // bf16 A_w[32768][512]
#define SZ_AW     33554432ull
#define OFF_PRE   38161920ull          // bf16 pre[32768][2432]
#define SZ_PRE    159383552ull
#define OFF_HBUF  197545472ull         // u32 hbuf[2 parity][2 d][128][320]: h<<16 | tag
#define SZ_HBUF   655360ull
#define OFF_CFIN  198200832ull         // f32 cfin[2][128][300]
#define SZ_CFIN   307200ull
#define OFF_RIDX  198508032ull         // int ridx[32768]
#define SZ_RIDX   131072ull
#define OFF_ELECT 198639104ull         // int elect[16] + podg[8][64]
#define SZ_ELECT  4096ull

// ---------------- helpers ----------------
__device__ __forceinline__ float bf2f(u16 u){
  union { u32 i; float f; } v; v.i = ((u32)u) << 16; return v.f;
}
__device__ __forceinline__ u16 f2bf(float f){
  union { float f; u32 i; } v; v.f = f;
  return (u16)((v.i + 0x7FFFu + ((v.i >> 16) & 1u)) >> 16);
}
__device__ __forceinline__ float sigm(float x){
  return __builtin_amdgcn_rcpf(1.0f + __builtin_amdgcn_exp2f(-1.442695040888963f * x));
}
__device__ __forceinline__ float tanh_(float x){
  return 1.0f - 2.0f * __builtin_amdgcn_rcpf(1.0f + __builtin_amdgcn_exp2f(2.885390081777927f * x));
}

// ---------------- prep: char gate table = char_emb @ Wc_x + bc ----------------
__global__ void k_table(const float* __restrict__ cemb,
    const float* __restrict__ Wc_fw, const float* __restrict__ bc_fw,
    const float* __restrict__ Wc_bw, const float* __restrict__ bc_bw,
    u16* __restrict__ tableC)
{
  int bid = blockIdx.x;
  int d = (bid >= 101) ? 1 : 0;
  int e = bid - d*101;
  const float* W  = d ? Wc_bw : Wc_fw;
  const float* bc = d ? bc_bw : bc_fw;
  __shared__ float ce[100];
  int tid = threadIdx.x;
  if (tid < 100) ce[tid] = cemb[e*100 + tid];
  __syncthreads();
  for (int c = tid; c < 512; c += 256){
    int g = c >> 7, cc = c & 127;
    float v = 0.f;
    if (cc < 100){
      float s = bc[g*100 + cc];
      for (int k = 0; k < 100; ++k) s += ce[k] * W[k*400 + g*100 + cc];
      v = s;
    }
    tableC[((size_t)d*101 + e)*512 + c] = f2bf(v);
  }
}

// ---------------- prep: pack char Wh into MFMA B-frag order ----------------
__global__ void k_packC(const float* __restrict__ Wc_fw, const float* __restrict__ Wc_bw,
                        u16* __restrict__ packC)
{
  int idx = blockIdx.x*256 + threadIdx.x;     // < 131072
  int j    = idx & 7;
  int lane = (idx >> 3) & 63;
  int kq   = (idx >> 9) & 3;
  int g    = (idx >> 11) & 3;
  int tau  = (idx >> 13) & 7;
  int d    = idx >> 16;
  int k = kq*32 + ((lane >> 4) << 3) + j;
  int c = tau*16 + (lane & 15);
  const float* W = d ? Wc_bw : Wc_fw;
  float v = (k < 100 && c < 100) ? W[(100 + k)*400 + g*100 + c] : 0.f;
  packC[idx] = f2bf(v);
}

// ---------------- prep: pack word Wh into MFMA B-frag order ----------------
__global__ void k_packW(const float* __restrict__ Ww_fw, const float* __restrict__ Ww_bw,
                        u16* __restrict__ packW)
{
  int idx = blockIdx.x*256 + threadIdx.x;     // < 819200
  int j    = idx & 7;
  int lane = (idx >> 3) & 63;
  int rest = idx >> 9;            // kq + 10*(g + 4*(tau + 20*d))
  int kq = rest % 10;
  int r2 = rest / 10;
  int g  = r2 & 3;
  int r3 = r2 >> 2;
  int tau = r3 % 20;
  int d   = r3 / 20;
  int k = kq*32 + ((lane >> 4) << 3) + j;
  int c = tau*16 + (lane & 15);
  const float* W = d ? Ww_bw : Ww_fw;
  float v = (k < 300 && c < 300) ? W[(500 + k)*1200 + g*300 + c] : 0.f;
  packW[idx] = f2bf(v);
}

// ---------------- prep: Bt[n][k] = Ww_x^T (n-major) + bias pack ----------------
__global__ void k_packBt(const float* __restrict__ Ww_fw, const float* __restrict__ bw_fw,
                         const float* __restrict__ Ww_bw, const float* __restrict__ bw_bw,
                         u16* __restrict__ Bt, float* __restrict__ biasP)
{
  int idx = blockIdx.x*256 + threadIdx.x;     // < 2432*512
  int k = idx & 511;
  int n = idx >> 9;
  float v = 0.f;
  if (n < 2400 && k < 500){
    int d = (n >= 1200) ? 1 : 0;
    int c = n - d*1200;
    v = (d ? Ww_bw : Ww_fw)[k*1200 + c];
  }
  Bt[idx] = f2bf(v);
  if (k == 0){
    float bv = 0.f;
    if (n < 2400){
      int d = (n >= 1200) ? 1 : 0;
      int c = n - d*1200;
      bv = (d ? bw_bw : bw_fw)[c];
    }
    biasP[n] = bv;
  }
}

// ---------------- prep: counting-sort char rows by word length (desc) ----------------
__global__ void k_sortC(const int* __restrict__ wlen, int* __restrict__ ridx)
{
  __shared__ int hist[17];
  __shared__ int curs[17];
  int tid = threadIdx.x;
  if (tid < 17) hist[tid] = 0;
  __syncthreads();
  for (int r = tid; r < 32768; r += 256) atomicAdd(&hist[wlen[r]], 1);
  __syncthreads();
  if (tid == 0){
    int run = 0;
    for (int l = 16; l >= 1; --l){ curs[l] = run; run += hist[l]; }
  }
  __syncthreads();
  for (int r = tid; r < 32768; r += 256){
    int p = atomicAdd(&curs[wlen[r]], 1);
    ridx[p] = r;
  }
}

// ---------------- A_w word-emb gather ----------------
__global__ void k_embed(const int* __restrict__ wid, const float* __restrict__ wemb,
                        u16* __restrict__ A_w)
{
  int idx = blockIdx.x*256 + threadIdx.x;     // < 32768*64 chunks of 8
  int row = idx >> 6, ch = idx & 63, c0 = ch*8;
  int w = wid[row];
  u16 v[8] __attribute__((aligned(16)));
  #pragma unroll
  for (int jj = 0; jj < 8; ++jj){
    int c = c0 + jj;
    v[jj] = (c < 300) ? f2bf(wemb[(size_t)w*300 + c]) : (u16)0;
  }
  *(uint4*)&A_w[(size_t)row*512 + c0] = *(const uint4*)v;
}

// ---------------- char BiLSTM: 32 rows/WG, weights in registers, h in LDS ----------------
__global__ __launch_bounds__(256,1) void k_char(
    const int* __restrict__ ridx, const int* __restrict__ wlen, const int* __restrict__ cids,
    const u16* __restrict__ tableC, const u16* __restrict__ packC, u16* __restrict__ A_w)
{
  const int bid = blockIdx.x;
  const int d = bid & 1, grp = bid >> 1;
  const int tid = threadIdx.x;
  const int wave = tid >> 6, lane = tid & 63, q = lane >> 4, l = lane & 15;
  __shared__ int rows_s[32];
  __shared__ int lens_s[32];
  __shared__ int ids_s[512];
  __shared__ __align__(16) u16 hbf[32*136];   // stride 136 -> 2-way banks (free)
  if (tid < 32){ int r = ridx[grp*32 + tid]; rows_s[tid] = r; lens_s[tid] = wlen[r]; }
  __syncthreads();
  for (int i = tid; i < 512; i += 256) ids_s[i] = cids[rows_s[i >> 4]*16 + (i & 15)];
  for (int i = tid; i < 32*136; i += 256) hbf[i] = 0;
  bf16x8 wf[2][4][4];
  {
    const u16* pc = packC + (size_t)d*65536;
    #pragma unroll
    for (int ti = 0; ti < 2; ++ti){
      const int tau = wave*2 + ti;
      #pragma unroll
      for (int g = 0; g < 4; ++g)
        #pragma unroll
        for (int kq = 0; kq < 4; ++kq)
          wf[ti][g][kq] = *(const bf16x8*)&pc[(((tau*4 + g)*4 + kq)*64 + lane)*8];
    }
  }
  __syncthreads();
  int maxlen = 0;
  for (int i = 0; i < 32; ++i) maxlen = max(maxlen, lens_s[i]);
  int lenr[2][4];
  #pragma unroll
  for (int m = 0; m < 2; ++m)
    #pragma unroll
    for (int reg = 0; reg < 4; ++reg) lenr[m][reg] = lens_s[m*16 + q*4 + reg];
  float c_st[2][2][4] = {};
  const u16* tab = tableC + (size_t)d*101*512;
  for (int s = 0; s < maxlen; ++s){
    bf16x8 af[2][4];
    #pragma unroll
    for (int m = 0; m < 2; ++m)
      #pragma unroll
      for (int kq = 0; kq < 4; ++kq)
        af[m][kq] = *(const bf16x8*)&hbf[(m*16 + l)*136 + kq*32 + q*8];
    __syncthreads();   // reads of h_s done before anyone writes h_{s+1}
    int idv[2][4];
    #pragma unroll
    for (int m = 0; m < 2; ++m)
      #pragma unroll
      for (int reg = 0; reg < 4; ++reg){
        int len = lenr[m][reg];
        idv[m][reg] = (s < len) ? ids_s[(m*16 + q*4 + reg)*16 + (d ? (len-1-s) : s)] : -1;
      }
    #pragma unroll
    for (int ti = 0; ti < 2; ++ti){
      const int tau = wave*2 + ti;
      #pragma unroll
      for (int m = 0; m < 2; ++m){
        f32x4 acc[4];
        #pragma unroll
        for (int g = 0; g < 4; ++g)
          #pragma unroll
          for (int reg = 0; reg < 4; ++reg){
            int id = idv[m][reg];
            acc[g][reg] = (id >= 0) ? bf2f(tab[(size_t)id*512 + g*128 + tau*16 + l]) : 0.f;
          }
        #pragma unroll
        for (int kq = 0; kq < 4; ++kq)
          #pragma unroll
          for (int g = 0; g < 4; ++g)
            acc[g] = __builtin_amdgcn_mfma_f32_16x16x32_bf16(af[m][kq], wf[ti][g][kq], acc[g], 0, 0, 0);
        #pragma unroll
        for (int reg = 0; reg < 4; ++reg){
          float i_ = acc[0][reg], j_ = acc[1][reg], f_ = acc[2][reg], o_ = acc[3][reg];
          float cv = c_st[ti][m][reg];
          float cn = cv * sigm(f_ + 1.0f) + sigm(i_) * tanh_(j_);
          float hn = sigm(o_) * tanh_(cn);
          bool upd = s < lenr[m][reg];
          c_st[ti][m][reg] = upd ? cn : cv;
          int col = tau*16 + l;
          if (upd && col < 100) hbf[(m*16 + q*4 + reg)*136 + col] = f2bf(hn);
        }
      }
    }
    __syncthreads();
  }
  for (int i = tid; i < 3200; i += 256){
    int r = i / 100, c = i - r*100;
    A_w[(size_t)rows_s[r]*512 + 300 + d*100 + c] = hbf[r*136 + c];
  }
}

// ---------------- word-x GEMM: pre = A_w @ Bt^T + bias (128x128 tile) ----------------
__global__ __launch_bounds__(256,2) void k_gemm(const u16* __restrict__ Aw,
    const u16* __restrict__ Bt, const float* __restrict__ biasP, u16* __restrict__ pre)
{
  __shared__ __align__(16) u16 lA[128*40];
  __shared__ __align__(16) u16 lB[128*40];
  const int tid = threadIdx.x;
  const int m0 = blockIdx.x * 128, n0 = blockIdx.y * 128;
  const int wave = tid >> 6, lane = tid & 63, q = lane >> 4, l = lane & 15;
  const int wm = wave & 1, wn = wave >> 1;
  const f32x4 fz = {0.f, 0.f, 0.f, 0.f};
  f32x4 acc[4][4];
  #pragma unroll
  for (int i = 0; i < 4; ++i)
    #pragma unroll
    for (int j = 0; j < 4; ++j) acc[i][j] = fz;
  const int r0 = tid >> 2, off = (tid & 3)*8;
  for (int kk = 0; kk < 512; kk += 32){
    __syncthreads();
    #pragma unroll
    for (int r = 0; r < 2; ++r){
      int row = r*64 + r0;
      *(uint4*)&lA[row*40 + off] = *(const uint4*)&Aw[(size_t)(m0+row)*512 + kk + off];
      *(uint4*)&lB[row*40 + off] = *(const uint4*)&Bt[(size_t)(n0+row)*512 + kk + off];
    }
    __syncthreads();
    bf16x8 af[4], bf[4];
    #pragma unroll
    for (int i = 0; i < 4; ++i) af[i] = *(const bf16x8*)&lA[(wm*64 + i*16 + l)*40 + q*8];
    #pragma unroll
    for (int j = 0; j < 4; ++j) bf[j] = *(const bf16x8*)&lB[(wn*64 + j*16 + l)*40 + q*8];
    #pragma unroll
    for (int i = 0; i < 4; ++i)
      #pragma unroll
      for (int j = 0; j < 4; ++j)
        acc[i][j] = __builtin_amdgcn_mfma_f32_16x16x32_bf16(af[i], bf[j], acc[i][j], 0, 0, 0);
  }
  float bv[4];
  #pragma unroll
  for (int j = 0; j < 4; ++j) bv[j] = biasP[n0 + wn*64 + j*16 + l];
  #pragma unroll
  for (int i = 0; i < 4; ++i)
    #pragma unroll
    for (int j = 0; j < 4; ++j)
      #pragma unroll
      for (int reg = 0; reg < 4; ++reg){
        int row = m0 + wm*64 + i*16 + q*4 + reg;
        int col = n0 + wn*64 + j*16 + l;
        pre[(size_t)row*2432 + col] = f2bf(acc[i][j][reg] + bv[j]);
      }
}

// ---------------- word BiLSTM (R3): same-XCD groups via election, L2-coherent ----------------
// Election: each WG reads HW_REG_XCC_ID; consecutive same-XCD arrivals form pods
// of 10; first 8 pods become groups (pigeonhole: 256 WGs -> >=18 pods worst-case).
// All intra-group traffic uses sc0 (L1-bypass, L2-coherent) => ~200cy hops, not
// the ~2500cy IC hops of sc1/agent scope.
// Tag-in-data: h word = bf16<<16 | step. Detection==fetch (one poll round), no
// flag, no store-ack. Parity double-buffer; WAR-safe because a producer can only
// advance after consumers published (which is after their reads were consumed).
__global__ __launch_bounds__(256,1) void k_word(
    const int* __restrict__ slen, const u16* __restrict__ packW, const u16* __restrict__ pre,
    u32* __restrict__ hbuf, float* __restrict__ cfin, int* __restrict__ elect)
{
  __shared__ int sh_g, sh_j;
  const int tid = threadIdx.x;
  if (tid == 0){
    // hwreg(HW_REG_XCC_ID=20, offset=0, size=32) -> imm = 20 | (31<<11)
    u32 xcd = __builtin_amdgcn_s_getreg(20 | (31 << 11)) & 7u;
    int slot = atomicAdd(&elect[xcd], 1);
    int pod = slot / 10, rank = slot - pod*10;
    int* pg = elect + 16 + (int)xcd*64 + pod;
    int g;
    if (rank == 0){
      g = atomicAdd(&elect[8], 1);
      __hip_atomic_store(pg, g + 1, __ATOMIC_RELAXED, __HIP_MEMORY_SCOPE_AGENT);
    } else {
      int gu = 0;
      do {
        g = __hip_atomic_load(pg, __ATOMIC_RELAXED, __HIP_MEMORY_SCOPE_AGENT);
      } while (g == 0 && ++gu < (1 << 20));
      g -= 1;
    }
    sh_g = g; sh_j = rank;
  }
  __syncthreads();
  const int g8 = sh_g, j = sh_j;
  if (g8 < 0 || g8 >= 8) return;      // surplus WG
  const int d = g8 & 1, grp = g8 >> 1;
  const int wave = tid >> 6, lane = tid & 63, q = lane >> 4, l = lane & 15;
  const int tau = j + 10*(wave & 1);
  const int m = wave >> 1;
  __shared__ int slen_s[32];
  if (tid < 32) slen_s[tid] = slen[grp*32 + tid];
  bf16x8 wf[4][10];
  {
    const u16* pw = packW + ((size_t)(d*20 + tau))*4*10*512;
    #pragma unroll
    for (int gg = 0; gg < 4; ++gg)
      #pragma unroll
      for (int kq = 0; kq < 10; ++kq)
        wf[gg][kq] = *(const bf16x8*)&pw[((gg*10 + kq)*64 + lane)*8];
  }
  __syncthreads();
  int maxlen = 1;
  for (int i = 0; i < 32; ++i) maxlen = max(maxlen, slen_s[i]);
  int lenr[4];
  #pragma unroll
  for (int reg = 0; reg < 4; ++reg) lenr[reg] = slen_s[m*16 + q*4 + reg];
  float c_st[4] = {0.f, 0.f, 0.f, 0.f};
  u16  h_st[4] = {0, 0, 0, 0};
  const int colz = tau*16 + l;
  const bool colok = colz < 300;
  const int rowb0 = grp*32 + m*16 + q*4;
  const size_t HB = (size_t)2*128*320;          // per-parity u32 elements
  const u32* hb_rd0 = hbuf + ((size_t)(d*128 + grp*32 + m*16 + l))*320;
  u32* hb_wr0 = hbuf + ((size_t)(d*128 + rowb0))*320 + colz;
  for (int s = 0; s < maxlen; ++s){
    // pre loads issued BEFORE the poll (independent of h; overlap L2/HBM latency)
    u16 pu[4][4];
    #pragma unroll
    for (int gg = 0; gg < 4; ++gg)
      #pragma unroll
      for (int reg = 0; reg < 4; ++reg){
        int len = lenr[reg];
        bool ok = (s < len) && colok;
        int t = d ? (len-1-s) : s;
        pu[gg][reg] = ok ? pre[((size_t)((rowb0+reg)*256 + t))*2432 + d*1200 + gg*300 + colz] : (u16)0;
      }
    uint4 r[20];
    if (s == 0){
      const uint4 z = {0u, 0u, 0u, 0u};
      #pragma unroll
      for (int i = 0; i < 20; ++i) r[i] = z;   // h_0 = 0, no poll needed
    } else {
      const u32* hb = hb_rd0 + (size_t)(s & 1)*HB;
      int guard = 0;
      u32 mism;
      do {
        #pragma unroll
        for (int kq = 0; kq < 10; ++kq){
          asm volatile("global_load_dwordx4 %0, %1, off sc0"
                       : "=v"(r[2*kq])   : "v"(hb + kq*32 + q*8));
          asm volatile("global_load_dwordx4 %0, %1, off sc0"
                       : "=v"(r[2*kq+1]) : "v"(hb + kq*32 + q*8 + 4));
        }
        asm volatile("s_waitcnt vmcnt(0)" ::: "memory");
        u32 a = 0;
        #pragma unroll
        for (int i = 0; i < 20; ++i){
          a |= (r[i].x ^ (u32)s); a |= (r[i].y ^ (u32)s);
          a |= (r[i].z ^ (u32)s); a |= (r[i].w ^ (u32)s);
        }
        mism = a & 0xFFFFu;
      } while (mism && ++guard < (1 << 14));
    }
    // convert tagged u32 -> bf16 A-frags (take high 16 bits)
    bf16x8 af[10];
    #pragma unroll
    for (int kq = 0; kq < 10; ++kq){
      union { u32 u[4]; bf16x8 v; } t;
      t.u[0] = (r[2*kq].x   >> 16) | (r[2*kq].y   & 0xFFFF0000u);
      t.u[1] = (r[2*kq].z   >> 16) | (r[2*kq].w   & 0xFFFF0000u);
      t.u[2] = (r[2*kq+1].x >> 16) | (r[2*kq+1].y & 0xFFFF0000u);
      t.u[3] = (r[2*kq+1].z >> 16) | (r[2*kq+1].w & 0xFFFF0000u);
      af[kq] = t.v;
    }
    f32x4 acc[4];
    #pragma unroll
    for (int gg = 0; gg < 4; ++gg)
      #pragma unroll
      for (int reg = 0; reg < 4; ++reg) acc[gg][reg] = bf2f(pu[gg][reg]);
    #pragma unroll
    for (int kq = 0; kq < 10; ++kq)
      #pragma unroll
      for (int gg = 0; gg < 4; ++gg)
        acc[gg] = __builtin_amdgcn_mfma_f32_16x16x32_bf16(af[kq], wf[gg][kq], acc[gg], 0, 0, 0);
    #pragma unroll
    for (int reg = 0; reg < 4; ++reg){
      float i_ = acc[0][reg], j_ = acc[1][reg], f_ = acc[2][reg], o_ = acc[3][reg];
      float cv = c_st[reg];
      float cn = cv * sigm(f_ + 1.0f) + sigm(i_) * tanh_(j_);
      float hn = sigm(o_) * tanh_(cn);
      bool upd = s < lenr[reg];
      c_st[reg] = upd ? cn : cv;
      h_st[reg] = upd ? f2bf(hn) : h_st[reg];
    }
    // publish h_{s+1} with tag s+1 (always, incl. masked rows & pad cols)
    u32* hw = hb_wr0 + (size_t)((s+1) & 1)*HB;
    #pragma unroll
    for (int reg = 0; reg < 4; ++reg){
      u32 val = ((u32)h_st[reg] << 16) | (u32)(s + 1);
      asm volatile("global_store_dword %0, %1, off sc0"
                   :: "v"(hw + reg*320), "v"(val) : "memory");
    }
  }
  #pragma unroll
  for (int reg = 0; reg < 4; ++reg)
    if (colok)
      __hip_atomic_store(&cfin[((size_t)(d*128 + rowb0 + reg))*300 + colz], c_st[reg],
                         __ATOMIC_RELAXED, __HIP_MEMORY_SCOPE_AGENT);
}

// ---------------- final projection + log-softmax NLL ----------------
__global__ void k_final(const float* __restrict__ cfin, const float* __restrict__ Wp,
                        const float* __restrict__ bp, const int* __restrict__ labels,
                        float* __restrict__ out)
{
  __shared__ float lg[384];
  __shared__ float red[128];
  int tid = threadIdx.x;
  for (int t = tid; t < 384; t += 256){
    int bb = t / 3, k = t - bb*3;
    float s = bp[k];
    for (int n = 0; n < 600; ++n){
      float v = (n < 300) ? cfin[bb*300 + n] : cfin[(128 + bb)*300 + (n - 300)];
      s += v * Wp[n*3 + k];
    }
    lg[bb*3 + k] = s;
  }
  __syncthreads();
  if (tid < 128){
    float a = lg[tid*3], b2 = lg[tid*3+1], c = lg[tid*3+2];
    float mx = fmaxf(a, fmaxf(b2, c));
    float lse = mx + __logf(__expf(a-mx) + __expf(b2-mx) + __expf(c-mx));
    red[tid] = lg[tid*3 + labels[tid]] - lse;
  }
  __syncthreads();
  for (int off = 64; off > 0; off >>= 1){
    if (tid < off) red[tid] += red[tid + off];
    __syncthreads();
  }
  if (tid == 0) out[0] = -red[0] / 128.f;
}

// ---------------- launch ----------------
extern "C" void kernel_launch(void* const* d_in, const int* in_sizes, int n_in,
                              void* d_out, int out_size, void* d_ws, size_t ws_size,
                              hipStream_t stream)
{
  const int*   wid    = (const int*)d_in[0];
  const int*   slen   = (const int*)d_in[1];
  const int*   cids   = (const int*)d_in[2];
  const int*   wlen   = (const int*)d_in[3];
  const int*   labels = (const int*)d_in[4];
  const float* wemb   = (const float*)d_in[5];
  const float* cemb   = (const float*)d_in[6];
  const float* Wc_fw  = (const float*)d_in[7];
  const float* bc_fw  = (const float*)d_in[8];
  const float* Wc_bw  = (const float*)d_in[9];
  const float* bc_bw  = (const float*)d_in[10];
  const float* Ww_fw  = (const float*)d_in[11];
  const float* bw_fw  = (const float*)d_in[12];
  const float* Ww_bw  = (const float*)d_in[13];
  const float* bw_bw  = (const float*)d_in[14];
  const float* Wp     = (const float*)d_in[15];
  const float* bp     = (const float*)d_in[16];

  char* ws = (char*)d_ws;
  u16*   tableC = (u16*)(ws + OFF_TABLE);
  u16*   packC  = (u16*)(ws + OFF_PACKC);
  u16*   packW  = (u16*)(ws + OFF_PACKW);
  u16*   Bt     = (u16*)(ws + OFF_BT);
  float* biasP  = (float*)(ws + OFF_BIAS);
  u16*   A_w    = (u16*)(ws + OFF_AW);
  u16*   pre    = (u16*)(ws + OFF_PRE);
  u32*   hbuf   = (u32*)(ws + OFF_HBUF);
  float* cfin   = (float*)(ws + OFF_CFIN);
  int*   ridx   = (int*)(ws + OFF_RIDX);
  int*   elect  = (int*)(ws + OFF_ELECT);

  hipMemsetAsync(ws + OFF_HBUF,  0, SZ_HBUF,  stream);  // h0 = 0, tag 0 (both parities)
  hipMemsetAsync(ws + OFF_ELECT, 0, SZ_ELECT, stream);  // election state

  k_table <<<dim3(202),  dim3(256), 0, stream>>>(cemb, Wc_fw, bc_fw, Wc_bw, bc_bw, tableC);
  k_packC <<<dim3(512),  dim3(256), 0, stream>>>(Wc_fw, Wc_bw, packC);
  k_packW <<<dim3(3200), dim3(256), 0, stream>>>(Ww_fw, Ww_bw, packW);
  k_packBt<<<dim3(4864), dim3(256), 0, stream>>>(Ww_fw, bw_fw, Ww_bw, bw_bw, Bt, biasP);
  k_sortC <<<dim3(1),    dim3(256), 0, stream>>>(wlen, ridx);
  k_embed <<<dim3(8192), dim3(256), 0, stream>>>(wid, wemb, A_w);
  k_char  <<<dim3(2048), dim3(256), 0, stream>>>(ridx, wlen, cids, tableC, packC, A_w);
  k_gemm  <<<dim3(256, 19), dim3(256), 0, stream>>>(A_w, Bt, biasP, pre);
  k_word  <<<dim3(256),  dim3(256), 0, stream>>>(slen, packW, pre, hbuf, cfin, elect);
  k_final <<<dim3(1),    dim3(256), 0, stream>>>(cfin, Wp, bp, labels, (float*)d_out);
}

// Round 4
// 5114.070 us; speedup vs baseline: 1382.4345x; 1382.4345x over previous
//
#include <hip/hip_runtime.h>

typedef float f32x4 __attribute__((ext_vector_type(4)));
typedef short bf16x8 __attribute__((ext_vector_type(8)));
typedef unsigned short u16;
typedef unsigned int u32;
typedef unsigned long long u64;

// ---------------- problem constants ----------------
// B=128 T=256 L=16 NW=50000 DW=300 NC=100(+1) DC=100 HC=100 H=300 NT=3
// rows = B*T = 32768 words.
// char LSTM: K padded 128 (4 kq), Hc padded 128 (8 tiles of 16)
// word LSTM: K padded 320 (10 kq), H padded 320 (20 tiles of 16)
// word-x GEMM: M=32768, K=512 (500 pad), N=2432 (2*1200 pad)

// ---------------- ws layout ----------------
#define OFF_TABLE 0ull                 // bf16 [2][101][512]
#define SZ_TABLE  206848ull
#define OFF_PACKC 206848ull            // bf16 [2][8tau][4g][4kq][64][8]
#define SZ_PACKC  262144ull
#define OFF_PACKW 468992ull            // bf16 [2][20tau][4g][10kq][64][8]
#define SZ_PACKW  1638400ull
#define OFF_BT    2107392ull           // bf16 Bt[2432][512]
#define SZ_BT     2490368ull
#define OFF_BIAS  4597760ull           // f32 [2432]
#define SZ_BIAS   9728ull
#define OFF_AW    4607488ull           // bf16 A_w[32768][512]
#define SZ_AW     33554432ull
#define OFF_PRE   38161920ull          // bf16 pre[32768][2432]
#define SZ_PRE    159383552ull
#define OFF_HBUF  197545472ull         // u32 hbuf[2 parity][2 d][128][320]: h<<16 | tag
#define SZ_HBUF   655360ull
#define OFF_CFIN  198200832ull         // f32 cfin[2][128][300]
#define SZ_CFIN   307200ull
#define OFF_RIDX  198508032ull         // int ridx[32768]
#define SZ_RIDX   131072ull

// ---------------- helpers ----------------
__device__ __forceinline__ float bf2f(u16 u){
  union { u32 i; float f; } v; v.i = ((u32)u) << 16; return v.f;
}
__device__ __forceinline__ u16 f2bf(float f){
  union { float f; u32 i; } v; v.f = f;
  return (u16)((v.i + 0x7FFFu + ((v.i >> 16) & 1u)) >> 16);
}
__device__ __forceinline__ float sigm(float x){
  return __builtin_amdgcn_rcpf(1.0f + __builtin_amdgcn_exp2f(-1.442695040888963f * x));
}
__device__ __forceinline__ float tanh_(float x){
  return 1.0f - 2.0f * __builtin_amdgcn_rcpf(1.0f + __builtin_amdgcn_exp2f(2.885390081777927f * x));
}

// ---------------- prep: char gate table = char_emb @ Wc_x + bc ----------------
__global__ void k_table(const float* __restrict__ cemb,
    const float* __restrict__ Wc_fw, const float* __restrict__ bc_fw,
    const float* __restrict__ Wc_bw, const float* __restrict__ bc_bw,
    u16* __restrict__ tableC)
{
  int bid = blockIdx.x;
  int d = (bid >= 101) ? 1 : 0;
  int e = bid - d*101;
  const float* W  = d ? Wc_bw : Wc_fw;
  const float* bc = d ? bc_bw : bc_fw;
  __shared__ float ce[100];
  int tid = threadIdx.x;
  if (tid < 100) ce[tid] = cemb[e*100 + tid];
  __syncthreads();
  for (int c = tid; c < 512; c += 256){
    int g = c >> 7, cc = c & 127;
    float v = 0.f;
    if (cc < 100){
      float s = bc[g*100 + cc];
      for (int k = 0; k < 100; ++k) s += ce[k] * W[k*400 + g*100 + cc];
      v = s;
    }
    tableC[((size_t)d*101 + e)*512 + c] = f2bf(v);
  }
}

// ---------------- prep: pack char Wh into MFMA B-frag order ----------------
__global__ void k_packC(const float* __restrict__ Wc_fw, const float* __restrict__ Wc_bw,
                        u16* __restrict__ packC)
{
  int idx = blockIdx.x*256 + threadIdx.x;     // < 131072
  int j    = idx & 7;
  int lane = (idx >> 3) & 63;
  int kq   = (idx >> 9) & 3;
  int g    = (idx >> 11) & 3;
  int tau  = (idx >> 13) & 7;
  int d    = idx >> 16;
  int k = kq*32 + ((lane >> 4) << 3) + j;
  int c = tau*16 + (lane & 15);
  const float* W = d ? Wc_bw : Wc_fw;
  float v = (k < 100 && c < 100) ? W[(100 + k)*400 + g*100 + c] : 0.f;
  packC[idx] = f2bf(v);
}

// ---------------- prep: pack word Wh into MFMA B-frag order ----------------
__global__ void k_packW(const float* __restrict__ Ww_fw, const float* __restrict__ Ww_bw,
                        u16* __restrict__ packW)
{
  int idx = blockIdx.x*256 + threadIdx.x;     // < 819200
  int j    = idx & 7;
  int lane = (idx >> 3) & 63;
  int rest = idx >> 9;            // kq + 10*(g + 4*(tau + 20*d))
  int kq = rest % 10;
  int r2 = rest / 10;
  int g  = r2 & 3;
  int r3 = r2 >> 2;
  int tau = r3 % 20;
  int d   = r3 / 20;
  int k = kq*32 + ((lane >> 4) << 3) + j;
  int c = tau*16 + (lane & 15);
  const float* W = d ? Ww_bw : Ww_fw;
  float v = (k < 300 && c < 300) ? W[(500 + k)*1200 + g*300 + c] : 0.f;
  packW[idx] = f2bf(v);
}

// ---------------- prep: Bt[n][k] = Ww_x^T (n-major) + bias pack ----------------
__global__ void k_packBt(const float* __restrict__ Ww_fw, const float* __restrict__ bw_fw,
                         const float* __restrict__ Ww_bw, const float* __restrict__ bw_bw,
                         u16* __restrict__ Bt, float* __restrict__ biasP)
{
  int idx = blockIdx.x*256 + threadIdx.x;     // < 2432*512
  int k = idx & 511;
  int n = idx >> 9;
  float v = 0.f;
  if (n < 2400 && k < 500){
    int d = (n >= 1200) ? 1 : 0;
    int c = n - d*1200;
    v = (d ? Ww_bw : Ww_fw)[k*1200 + c];
  }
  Bt[idx] = f2bf(v);
  if (k == 0){
    float bv = 0.f;
    if (n < 2400){
      int d = (n >= 1200) ? 1 : 0;
      int c = n - d*1200;
      bv = (d ? bw_bw : bw_fw)[c];
    }
    biasP[n] = bv;
  }
}

// ---------------- prep: counting-sort char rows by word length (desc) ----------------
__global__ void k_sortC(const int* __restrict__ wlen, int* __restrict__ ridx)
{
  __shared__ int hist[17];
  __shared__ int curs[17];
  int tid = threadIdx.x;
  if (tid < 17) hist[tid] = 0;
  __syncthreads();
  for (int r = tid; r < 32768; r += 256) atomicAdd(&hist[wlen[r]], 1);
  __syncthreads();
  if (tid == 0){
    int run = 0;
    for (int l = 16; l >= 1; --l){ curs[l] = run; run += hist[l]; }
  }
  __syncthreads();
  for (int r = tid; r < 32768; r += 256){
    int p = atomicAdd(&curs[wlen[r]], 1);
    ridx[p] = r;
  }
}

// ---------------- A_w word-emb gather ----------------
__global__ void k_embed(const int* __restrict__ wid, const float* __restrict__ wemb,
                        u16* __restrict__ A_w)
{
  int idx = blockIdx.x*256 + threadIdx.x;     // < 32768*64 chunks of 8
  int row = idx >> 6, ch = idx & 63, c0 = ch*8;
  int w = wid[row];
  u16 v[8] __attribute__((aligned(16)));
  #pragma unroll
  for (int jj = 0; jj < 8; ++jj){
    int c = c0 + jj;
    v[jj] = (c < 300) ? f2bf(wemb[(size_t)w*300 + c]) : (u16)0;
  }
  *(uint4*)&A_w[(size_t)row*512 + c0] = *(const uint4*)v;
}

// ---------------- char BiLSTM: 32 rows/WG, weights in registers, h in LDS ----------------
__global__ __launch_bounds__(256,1) void k_char(
    const int* __restrict__ ridx, const int* __restrict__ wlen, const int* __restrict__ cids,
    const u16* __restrict__ tableC, const u16* __restrict__ packC, u16* __restrict__ A_w)
{
  const int bid = blockIdx.x;
  const int d = bid & 1, grp = bid >> 1;
  const int tid = threadIdx.x;
  const int wave = tid >> 6, lane = tid & 63, q = lane >> 4, l = lane & 15;
  __shared__ int rows_s[32];
  __shared__ int lens_s[32];
  __shared__ int ids_s[512];
  __shared__ __align__(16) u16 hbf[32*136];   // stride 136 -> 2-way banks (free)
  if (tid < 32){ int r = ridx[grp*32 + tid]; rows_s[tid] = r; lens_s[tid] = wlen[r]; }
  __syncthreads();
  for (int i = tid; i < 512; i += 256) ids_s[i] = cids[rows_s[i >> 4]*16 + (i & 15)];
  for (int i = tid; i < 32*136; i += 256) hbf[i] = 0;
  bf16x8 wf[2][4][4];
  {
    const u16* pc = packC + (size_t)d*65536;
    #pragma unroll
    for (int ti = 0; ti < 2; ++ti){
      const int tau = wave*2 + ti;
      #pragma unroll
      for (int g = 0; g < 4; ++g)
        #pragma unroll
        for (int kq = 0; kq < 4; ++kq)
          wf[ti][g][kq] = *(const bf16x8*)&pc[(((tau*4 + g)*4 + kq)*64 + lane)*8];
    }
  }
  __syncthreads();
  int maxlen = 0;
  for (int i = 0; i < 32; ++i) maxlen = max(maxlen, lens_s[i]);
  int lenr[2][4];
  #pragma unroll
  for (int m = 0; m < 2; ++m)
    #pragma unroll
    for (int reg = 0; reg < 4; ++reg) lenr[m][reg] = lens_s[m*16 + q*4 + reg];
  float c_st[2][2][4] = {};
  const u16* tab = tableC + (size_t)d*101*512;
  for (int s = 0; s < maxlen; ++s){
    bf16x8 af[2][4];
    #pragma unroll
    for (int m = 0; m < 2; ++m)
      #pragma unroll
      for (int kq = 0; kq < 4; ++kq)
        af[m][kq] = *(const bf16x8*)&hbf[(m*16 + l)*136 + kq*32 + q*8];
    __syncthreads();   // reads of h_s done before anyone writes h_{s+1}
    int idv[2][4];
    #pragma unroll
    for (int m = 0; m < 2; ++m)
      #pragma unroll
      for (int reg = 0; reg < 4; ++reg){
        int len = lenr[m][reg];
        idv[m][reg] = (s < len) ? ids_s[(m*16 + q*4 + reg)*16 + (d ? (len-1-s) : s)] : -1;
      }
    #pragma unroll
    for (int ti = 0; ti < 2; ++ti){
      const int tau = wave*2 + ti;
      #pragma unroll
      for (int m = 0; m < 2; ++m){
        f32x4 acc[4];
        #pragma unroll
        for (int g = 0; g < 4; ++g)
          #pragma unroll
          for (int reg = 0; reg < 4; ++reg){
            int id = idv[m][reg];
            acc[g][reg] = (id >= 0) ? bf2f(tab[(size_t)id*512 + g*128 + tau*16 + l]) : 0.f;
          }
        #pragma unroll
        for (int kq = 0; kq < 4; ++kq)
          #pragma unroll
          for (int g = 0; g < 4; ++g)
            acc[g] = __builtin_amdgcn_mfma_f32_16x16x32_bf16(af[m][kq], wf[ti][g][kq], acc[g], 0, 0, 0);
        #pragma unroll
        for (int reg = 0; reg < 4; ++reg){
          float i_ = acc[0][reg], j_ = acc[1][reg], f_ = acc[2][reg], o_ = acc[3][reg];
          float cv = c_st[ti][m][reg];
          float cn = cv * sigm(f_ + 1.0f) + sigm(i_) * tanh_(j_);
          float hn = sigm(o_) * tanh_(cn);
          bool upd = s < lenr[m][reg];
          c_st[ti][m][reg] = upd ? cn : cv;
          int col = tau*16 + l;
          if (upd && col < 100) hbf[(m*16 + q*4 + reg)*136 + col] = f2bf(hn);
        }
      }
    }
    __syncthreads();
  }
  for (int i = tid; i < 3200; i += 256){
    int r = i / 100, c = i - r*100;
    A_w[(size_t)rows_s[r]*512 + 300 + d*100 + c] = hbf[r*136 + c];
  }
}

// ---------------- word-x GEMM: pre = A_w @ Bt^T + bias (128x128 tile) ----------------
__global__ __launch_bounds__(256,2) void k_gemm(const u16* __restrict__ Aw,
    const u16* __restrict__ Bt, const float* __restrict__ biasP, u16* __restrict__ pre)
{
  __shared__ __align__(16) u16 lA[128*40];
  __shared__ __align__(16) u16 lB[128*40];
  const int tid = threadIdx.x;
  const int m0 = blockIdx.x * 128, n0 = blockIdx.y * 128;
  const int wave = tid >> 6, lane = tid & 63, q = lane >> 4, l = lane & 15;
  const int wm = wave & 1, wn = wave >> 1;
  const f32x4 fz = {0.f, 0.f, 0.f, 0.f};
  f32x4 acc[4][4];
  #pragma unroll
  for (int i = 0; i < 4; ++i)
    #pragma unroll
    for (int j = 0; j < 4; ++j) acc[i][j] = fz;
  const int r0 = tid >> 2, off = (tid & 3)*8;
  for (int kk = 0; kk < 512; kk += 32){
    __syncthreads();
    #pragma unroll
    for (int r = 0; r < 2; ++r){
      int row = r*64 + r0;
      *(uint4*)&lA[row*40 + off] = *(const uint4*)&Aw[(size_t)(m0+row)*512 + kk + off];
      *(uint4*)&lB[row*40 + off] = *(const uint4*)&Bt[(size_t)(n0+row)*512 + kk + off];
    }
    __syncthreads();
    bf16x8 af[4], bf[4];
    #pragma unroll
    for (int i = 0; i < 4; ++i) af[i] = *(const bf16x8*)&lA[(wm*64 + i*16 + l)*40 + q*8];
    #pragma unroll
    for (int j = 0; j < 4; ++j) bf[j] = *(const bf16x8*)&lB[(wn*64 + j*16 + l)*40 + q*8];
    #pragma unroll
    for (int i = 0; i < 4; ++i)
      #pragma unroll
      for (int j = 0; j < 4; ++j)
        acc[i][j] = __builtin_amdgcn_mfma_f32_16x16x32_bf16(af[i], bf[j], acc[i][j], 0, 0, 0);
  }
  float bv[4];
  #pragma unroll
  for (int j = 0; j < 4; ++j) bv[j] = biasP[n0 + wn*64 + j*16 + l];
  #pragma unroll
  for (int i = 0; i < 4; ++i)
    #pragma unroll
    for (int j = 0; j < 4; ++j)
      #pragma unroll
      for (int reg = 0; reg < 4; ++reg){
        int row = m0 + wm*64 + i*16 + q*4 + reg;
        int col = n0 + wn*64 + j*16 + l;
        pre[(size_t)row*2432 + col] = f2bf(acc[i][j][reg] + bv[j]);
      }
}

// ---------------- word BiLSTM (R4): fixed 80-WG groups, IC-coherent tag-in-data ----------------
// R2's sc1/IC regime (proven correct & deterministic) + R3's tag-in-data idea:
// each h word = bf16(h)<<16 | step-tag, parity double-buffered. One poll round
// both detects readiness and fetches h (single IC round-trip), no flags, no
// store-ack vmcnt. WAR-safe: a wave publishes tag s+1 only after its tag-s
// loads were consumed (true data dep through MFMA), and parity p is only
// overwritten at tag s+2 after seeing ALL tag s+1.
__global__ __launch_bounds__(256,1) void k_word(
    const int* __restrict__ slen, const u16* __restrict__ packW, const u16* __restrict__ pre,
    u32* __restrict__ hbuf, float* __restrict__ cfin)
{
  const int b = blockIdx.x;
  const int g8 = b & 7;               // group: (d, batch-quarter)
  const int d = g8 & 1, grp = g8 >> 1;
  const int j = b >> 3;               // member 0..9, owns h-tiles {j, j+10}
  const int tid = threadIdx.x;
  const int wave = tid >> 6, lane = tid & 63, q = lane >> 4, l = lane & 15;
  const int tau = j + 10*(wave & 1);
  const int m = wave >> 1;
  __shared__ int slen_s[32];
  if (tid < 32) slen_s[tid] = slen[grp*32 + tid];
  bf16x8 wf[4][10];
  {
    const u16* pw = packW + ((size_t)(d*20 + tau))*4*10*512;
    #pragma unroll
    for (int gg = 0; gg < 4; ++gg)
      #pragma unroll
      for (int kq = 0; kq < 10; ++kq)
        wf[gg][kq] = *(const bf16x8*)&pw[((gg*10 + kq)*64 + lane)*8];
  }
  __syncthreads();
  int maxlen = 1;
  for (int i = 0; i < 32; ++i) maxlen = max(maxlen, slen_s[i]);
  int lenr[4];
  #pragma unroll
  for (int reg = 0; reg < 4; ++reg) lenr[reg] = slen_s[m*16 + q*4 + reg];
  float c_st[4] = {0.f, 0.f, 0.f, 0.f};
  u16  h_st[4] = {0, 0, 0, 0};
  const int colz = tau*16 + l;
  const bool colok = colz < 300;
  const int rowb0 = grp*32 + m*16 + q*4;
  const size_t HB = (size_t)2*128*320;          // per-parity u32 elements
  const u32* hb_rd0 = hbuf + ((size_t)(d*128 + grp*32 + m*16 + l))*320;
  u32* hb_wr0 = hbuf + ((size_t)(d*128 + rowb0))*320 + colz;
  for (int s = 0; s < maxlen; ++s){
    // pre loads issued BEFORE the poll (independent of h; overlap HBM/L2 latency)
    u16 pu[4][4];
    #pragma unroll
    for (int gg = 0; gg < 4; ++gg)
      #pragma unroll
      for (int reg = 0; reg < 4; ++reg){
        int len = lenr[reg];
        bool ok = (s < len) && colok;
        int t = d ? (len-1-s) : s;
        pu[gg][reg] = ok ? pre[((size_t)((rowb0+reg)*256 + t))*2432 + d*1200 + gg*300 + colz] : (u16)0;
      }
    u64 r[40];
    if (s == 0){
      #pragma unroll
      for (int i = 0; i < 40; ++i) r[i] = 0ull;   // h_0 = 0, no poll needed
    } else {
      const u32* hb = hb_rd0 + (size_t)(s & 1)*HB;
      const u32 tag = (u32)s;
      int guard = 0;
      u32 mism;
      do {
        #pragma unroll
        for (int kq = 0; kq < 10; ++kq)
          #pragma unroll
          for (int h4 = 0; h4 < 4; ++h4)
            r[kq*4 + h4] = __hip_atomic_load((u64*)(hb + kq*32 + q*8 + h4*2),
                                             __ATOMIC_RELAXED, __HIP_MEMORY_SCOPE_AGENT);
        u32 a = 0;
        #pragma unroll
        for (int i = 0; i < 40; ++i){
          a |= ((u32)r[i] ^ tag);
          a |= ((u32)(r[i] >> 32) ^ tag);
        }
        mism = a & 0xFFFFu;
      } while (mism && ++guard < (1 << 14));
    }
    // tagged u64 pairs -> bf16 A-frags (high 16 bits of each u32)
    bf16x8 af[10];
    #pragma unroll
    for (int kq = 0; kq < 10; ++kq){
      union { u32 u[4]; bf16x8 v; } t;
      #pragma unroll
      for (int h4 = 0; h4 < 4; ++h4){
        u64 w = r[kq*4 + h4];
        t.u[h4] = ((u32)w >> 16) | ((u32)(w >> 32) & 0xFFFF0000u);
      }
      af[kq] = t.v;
    }
    f32x4 acc[4];
    #pragma unroll
    for (int gg = 0; gg < 4; ++gg)
      #pragma unroll
      for (int reg = 0; reg < 4; ++reg) acc[gg][reg] = bf2f(pu[gg][reg]);
    #pragma unroll
    for (int kq = 0; kq < 10; ++kq)
      #pragma unroll
      for (int gg = 0; gg < 4; ++gg)
        acc[gg] = __builtin_amdgcn_mfma_f32_16x16x32_bf16(af[kq], wf[gg][kq], acc[gg], 0, 0, 0);
    #pragma unroll
    for (int reg = 0; reg < 4; ++reg){
      float i_ = acc[0][reg], j_ = acc[1][reg], f_ = acc[2][reg], o_ = acc[3][reg];
      float cv = c_st[reg];
      float cn = cv * sigm(f_ + 1.0f) + sigm(i_) * tanh_(j_);
      float hn = sigm(o_) * tanh_(cn);
      bool upd = s < lenr[reg];
      c_st[reg] = upd ? cn : cv;
      h_st[reg] = upd ? f2bf(hn) : h_st[reg];
    }
    // publish h_{s+1} with tag s+1 (always, incl. masked rows & pad cols)
    u32* hw = hb_wr0 + (size_t)((s+1) & 1)*HB;
    #pragma unroll
    for (int reg = 0; reg < 4; ++reg){
      u32 val = ((u32)h_st[reg] << 16) | (u32)((s + 1) & 0xFFFF);
      __hip_atomic_store(hw + reg*320, val, __ATOMIC_RELAXED, __HIP_MEMORY_SCOPE_AGENT);
    }
  }
  #pragma unroll
  for (int reg = 0; reg < 4; ++reg)
    if (colok) cfin[((size_t)(d*128 + rowb0 + reg))*300 + colz] = c_st[reg];
}

// ---------------- final projection + log-softmax NLL ----------------
__global__ void k_final(const float* __restrict__ cfin, const float* __restrict__ Wp,
                        const float* __restrict__ bp, const int* __restrict__ labels,
                        float* __restrict__ out)
{
  __shared__ float lg[384];
  __shared__ float red[128];
  int tid = threadIdx.x;
  for (int t = tid; t < 384; t += 256){
    int bb = t / 3, k = t - bb*3;
    float s = bp[k];
    for (int n = 0; n < 600; ++n){
      float v = (n < 300) ? cfin[bb*300 + n] : cfin[(128 + bb)*300 + (n - 300)];
      s += v * Wp[n*3 + k];
    }
    lg[bb*3 + k] = s;
  }
  __syncthreads();
  if (tid < 128){
    float a = lg[tid*3], b2 = lg[tid*3+1], c = lg[tid*3+2];
    float mx = fmaxf(a, fmaxf(b2, c));
    float lse = mx + __logf(__expf(a-mx) + __expf(b2-mx) + __expf(c-mx));
    red[tid] = lg[tid*3 + labels[tid]] - lse;
  }
  __syncthreads();
  for (int off = 64; off > 0; off >>= 1){
    if (tid < off) red[tid] += red[tid + off];
    __syncthreads();
  }
  if (tid == 0) out[0] = -red[0] / 128.f;
}

// ---------------- launch ----------------
extern "C" void kernel_launch(void* const* d_in, const int* in_sizes, int n_in,
                              void* d_out, int out_size, void* d_ws, size_t ws_size,
                              hipStream_t stream)
{
  const int*   wid    = (const int*)d_in[0];
  const int*   slen   = (const int*)d_in[1];
  const int*   cids   = (const int*)d_in[2];
  const int*   wlen   = (const int*)d_in[3];
  const int*   labels = (const int*)d_in[4];
  const float* wemb   = (const float*)d_in[5];
  const float* cemb   = (const float*)d_in[6];
  const float* Wc_fw  = (const float*)d_in[7];
  const float* bc_fw  = (const float*)d_in[8];
  const float* Wc_bw  = (const float*)d_in[9];
  const float* bc_bw  = (const float*)d_in[10];
  const float* Ww_fw  = (const float*)d_in[11];
  const float* bw_fw  = (const float*)d_in[12];
  const float* Ww_bw  = (const float*)d_in[13];
  const float* bw_bw  = (const float*)d_in[14];
  const float* Wp     = (const float*)d_in[15];
  const float* bp     = (const float*)d_in[16];

  char* ws = (char*)d_ws;
  u16*   tableC = (u16*)(ws + OFF_TABLE);
  u16*   packC  = (u16*)(ws + OFF_PACKC);
  u16*   packW  = (u16*)(ws + OFF_PACKW);
  u16*   Bt     = (u16*)(ws + OFF_BT);
  float* biasP  = (float*)(ws + OFF_BIAS);
  u16*   A_w    = (u16*)(ws + OFF_AW);
  u16*   pre    = (u16*)(ws + OFF_PRE);
  u32*   hbuf   = (u32*)(ws + OFF_HBUF);
  float* cfin   = (float*)(ws + OFF_CFIN);
  int*   ridx   = (int*)(ws + OFF_RIDX);

  hipMemsetAsync(ws + OFF_HBUF, 0, SZ_HBUF, stream);   // h0 = 0, tag 0 (both parities)

  k_table <<<dim3(202),  dim3(256), 0, stream>>>(cemb, Wc_fw, bc_fw, Wc_bw, bc_bw, tableC);
  k_packC <<<dim3(512),  dim3(256), 0, stream>>>(Wc_fw, Wc_bw, packC);
  k_packW <<<dim3(3200), dim3(256), 0, stream>>>(Ww_fw, Ww_bw, packW);
  k_packBt<<<dim3(4864), dim3(256), 0, stream>>>(Ww_fw, bw_fw, Ww_bw, bw_bw, Bt, biasP);
  k_sortC <<<dim3(1),    dim3(256), 0, stream>>>(wlen, ridx);
  k_embed <<<dim3(8192), dim3(256), 0, stream>>>(wid, wemb, A_w);
  k_char  <<<dim3(2048), dim3(256), 0, stream>>>(ridx, wlen, cids, tableC, packC, A_w);
  k_gemm  <<<dim3(256, 19), dim3(256), 0, stream>>>(A_w, Bt, biasP, pre);
  k_word  <<<dim3(80),   dim3(256), 0, stream>>>(slen, packW, pre, hbuf, cfin);
  k_final <<<dim3(1),    dim3(256), 0, stream>>>(cfin, Wp, bp, labels, (float*)d_out);
}

// Round 6
// 2762.520 us; speedup vs baseline: 2559.2090x; 1.8512x over previous
//
#include <hip/hip_runtime.h>

typedef float f32x4 __attribute__((ext_vector_type(4)));
typedef short bf16x8 __attribute__((ext_vector_type(8)));
typedef unsigned short u16;
typedef unsigned int u32;
typedef unsigned long long u64;

// ---------------- problem constants ----------------
// B=128 T=256 L=16 NW=50000 DW=300 NC=100(+1) DC=100 HC=100 H=300 NT=3
// rows = B*T = 32768 words.
// char LSTM: K padded 128 (4 kq), Hc padded 128 (8 tiles of 16)
// word LSTM: K padded 320 (10 kq), H padded 320 (20 tiles of 16)
// word-x GEMM: M=32768, K=512 (500 pad), N=2432 (2*1200 pad)

// ---------------- ws layout ----------------
#define OFF_TABLE 0ull                 // bf16 [2][101][512]
#define SZ_TABLE  206848ull
#define OFF_PACKC 206848ull            // bf16 [2][8tau][4g][4kq][64][8]
#define SZ_PACKC  262144ull
#define OFF_PACKW 468992ull            // bf16 [2][20tau][4g][10kq][64][8]
#define SZ_PACKW  1638400ull
#define OFF_BT    2107392ull           // bf16 Bt[2432][512]
#define SZ_BT     2490368ull
#define OFF_BIAS  4597760ull           // f32 [2432]
#define SZ_BIAS   9728ull
#define OFF_AW    4607488ull           // bf16 A_w[32768][512]
#define SZ_AW     33554432ull
#define OFF_PRE   38161920ull          // bf16 pre[32768][2432]
#define SZ_PRE    159383552ull
#define OFF_HBUF  197545472ull         // bf16 hbuf[2 parity][2 d][128][320]
#define SZ_HBUF   327680ull
#define OFF_CFIN  197873152ull         // f32 cfin[2][128][300]
#define SZ_CFIN   307200ull
#define OFF_RIDX  198180352ull         // int ridx[32768]
#define SZ_RIDX   131072ull
#define OFF_CNT   198311424ull         // int flags[8 group][64] (40 used, 256B/group)
#define SZ_CNT    2048ull

// ---------------- helpers ----------------
__device__ __forceinline__ float bf2f(u16 u){
  union { u32 i; float f; } v; v.i = ((u32)u) << 16; return v.f;
}
__device__ __forceinline__ u16 f2bf(float f){
  union { float f; u32 i; } v; v.f = f;
  return (u16)((v.i + 0x7FFFu + ((v.i >> 16) & 1u)) >> 16);
}
__device__ __forceinline__ float sigm(float x){
  return __builtin_amdgcn_rcpf(1.0f + __builtin_amdgcn_exp2f(-1.442695040888963f * x));
}
__device__ __forceinline__ float tanh_(float x){
  return 1.0f - 2.0f * __builtin_amdgcn_rcpf(1.0f + __builtin_amdgcn_exp2f(2.885390081777927f * x));
}

// ---------------- prep: char gate table = char_emb @ Wc_x + bc ----------------
__global__ void k_table(const float* __restrict__ cemb,
    const float* __restrict__ Wc_fw, const float* __restrict__ bc_fw,
    const float* __restrict__ Wc_bw, const float* __restrict__ bc_bw,
    u16* __restrict__ tableC)
{
  int bid = blockIdx.x;
  int d = (bid >= 101) ? 1 : 0;
  int e = bid - d*101;
  const float* W  = d ? Wc_bw : Wc_fw;
  const float* bc = d ? bc_bw : bc_fw;
  __shared__ float ce[100];
  int tid = threadIdx.x;
  if (tid < 100) ce[tid] = cemb[e*100 + tid];
  __syncthreads();
  for (int c = tid; c < 512; c += 256){
    int g = c >> 7, cc = c & 127;
    float v = 0.f;
    if (cc < 100){
      float s = bc[g*100 + cc];
      for (int k = 0; k < 100; ++k) s += ce[k] * W[k*400 + g*100 + cc];
      v = s;
    }
    tableC[((size_t)d*101 + e)*512 + c] = f2bf(v);
  }
}

// ---------------- prep: pack char Wh into MFMA B-frag order ----------------
__global__ void k_packC(const float* __restrict__ Wc_fw, const float* __restrict__ Wc_bw,
                        u16* __restrict__ packC)
{
  int idx = blockIdx.x*256 + threadIdx.x;     // < 131072
  int j    = idx & 7;
  int lane = (idx >> 3) & 63;
  int kq   = (idx >> 9) & 3;
  int g    = (idx >> 11) & 3;
  int tau  = (idx >> 13) & 7;
  int d    = idx >> 16;
  int k = kq*32 + ((lane >> 4) << 3) + j;
  int c = tau*16 + (lane & 15);
  const float* W = d ? Wc_bw : Wc_fw;
  float v = (k < 100 && c < 100) ? W[(100 + k)*400 + g*100 + c] : 0.f;
  packC[idx] = f2bf(v);
}

// ---------------- prep: pack word Wh into MFMA B-frag order ----------------
__global__ void k_packW(const float* __restrict__ Ww_fw, const float* __restrict__ Ww_bw,
                        u16* __restrict__ packW)
{
  int idx = blockIdx.x*256 + threadIdx.x;     // < 819200
  int j    = idx & 7;
  int lane = (idx >> 3) & 63;
  int rest = idx >> 9;            // kq + 10*(g + 4*(tau + 20*d))
  int kq = rest % 10;
  int r2 = rest / 10;
  int g  = r2 & 3;
  int r3 = r2 >> 2;
  int tau = r3 % 20;
  int d   = r3 / 20;
  int k = kq*32 + ((lane >> 4) << 3) + j;
  int c = tau*16 + (lane & 15);
  const float* W = d ? Ww_bw : Ww_fw;
  float v = (k < 300 && c < 300) ? W[(500 + k)*1200 + g*300 + c] : 0.f;
  packW[idx] = f2bf(v);
}

// ---------------- prep: Bt[n][k] = Ww_x^T (n-major) + bias pack ----------------
__global__ void k_packBt(const float* __restrict__ Ww_fw, const float* __restrict__ bw_fw,
                         const float* __restrict__ Ww_bw, const float* __restrict__ bw_bw,
                         u16* __restrict__ Bt, float* __restrict__ biasP)
{
  int idx = blockIdx.x*256 + threadIdx.x;     // < 2432*512
  int k = idx & 511;
  int n = idx >> 9;
  float v = 0.f;
  if (n < 2400 && k < 500){
    int d = (n >= 1200) ? 1 : 0;
    int c = n - d*1200;
    v = (d ? Ww_bw : Ww_fw)[k*1200 + c];
  }
  Bt[idx] = f2bf(v);
  if (k == 0){
    float bv = 0.f;
    if (n < 2400){
      int d = (n >= 1200) ? 1 : 0;
      int c = n - d*1200;
      bv = (d ? bw_bw : bw_fw)[c];
    }
    biasP[n] = bv;
  }
}

// ---------------- prep: counting-sort char rows by word length (desc) ----------------
__global__ void k_sortC(const int* __restrict__ wlen, int* __restrict__ ridx)
{
  __shared__ int hist[17];
  __shared__ int curs[17];
  int tid = threadIdx.x;
  if (tid < 17) hist[tid] = 0;
  __syncthreads();
  for (int r = tid; r < 32768; r += 256) atomicAdd(&hist[wlen[r]], 1);
  __syncthreads();
  if (tid == 0){
    int run = 0;
    for (int l = 16; l >= 1; --l){ curs[l] = run; run += hist[l]; }
  }
  __syncthreads();
  for (int r = tid; r < 32768; r += 256){
    int p = atomicAdd(&curs[wlen[r]], 1);
    ridx[p] = r;
  }
}

// ---------------- A_w word-emb gather ----------------
__global__ void k_embed(const int* __restrict__ wid, const float* __restrict__ wemb,
                        u16* __restrict__ A_w)
{
  int idx = blockIdx.x*256 + threadIdx.x;     // < 32768*64 chunks of 8
  int row = idx >> 6, ch = idx & 63, c0 = ch*8;
  int w = wid[row];
  u16 v[8] __attribute__((aligned(16)));
  #pragma unroll
  for (int jj = 0; jj < 8; ++jj){
    int c = c0 + jj;
    v[jj] = (c < 300) ? f2bf(wemb[(size_t)w*300 + c]) : (u16)0;
  }
  *(uint4*)&A_w[(size_t)row*512 + c0] = *(const uint4*)v;
}

// ---------------- char BiLSTM: 32 rows/WG, weights in registers, h in LDS ----------------
__global__ __launch_bounds__(256,1) void k_char(
    const int* __restrict__ ridx, const int* __restrict__ wlen, const int* __restrict__ cids,
    const u16* __restrict__ tableC, const u16* __restrict__ packC, u16* __restrict__ A_w)
{
  const int bid = blockIdx.x;
  const int d = bid & 1, grp = bid >> 1;
  const int tid = threadIdx.x;
  const int wave = tid >> 6, lane = tid & 63, q = lane >> 4, l = lane & 15;
  __shared__ int rows_s[32];
  __shared__ int lens_s[32];
  __shared__ int ids_s[512];
  __shared__ __align__(16) u16 hbf[32*136];   // stride 136 -> 2-way banks (free)
  if (tid < 32){ int r = ridx[grp*32 + tid]; rows_s[tid] = r; lens_s[tid] = wlen[r]; }
  __syncthreads();
  for (int i = tid; i < 512; i += 256) ids_s[i] = cids[rows_s[i >> 4]*16 + (i & 15)];
  for (int i = tid; i < 32*136; i += 256) hbf[i] = 0;
  bf16x8 wf[2][4][4];
  {
    const u16* pc = packC + (size_t)d*65536;
    #pragma unroll
    for (int ti = 0; ti < 2; ++ti){
      const int tau = wave*2 + ti;
      #pragma unroll
      for (int g = 0; g < 4; ++g)
        #pragma unroll
        for (int kq = 0; kq < 4; ++kq)
          wf[ti][g][kq] = *(const bf16x8*)&pc[(((tau*4 + g)*4 + kq)*64 + lane)*8];
    }
  }
  __syncthreads();
  int maxlen = 0;
  for (int i = 0; i < 32; ++i) maxlen = max(maxlen, lens_s[i]);
  int lenr[2][4];
  #pragma unroll
  for (int m = 0; m < 2; ++m)
    #pragma unroll
    for (int reg = 0; reg < 4; ++reg) lenr[m][reg] = lens_s[m*16 + q*4 + reg];
  float c_st[2][2][4] = {};
  const u16* tab = tableC + (size_t)d*101*512;
  for (int s = 0; s < maxlen; ++s){
    bf16x8 af[2][4];
    #pragma unroll
    for (int m = 0; m < 2; ++m)
      #pragma unroll
      for (int kq = 0; kq < 4; ++kq)
        af[m][kq] = *(const bf16x8*)&hbf[(m*16 + l)*136 + kq*32 + q*8];
    __syncthreads();   // reads of h_s done before anyone writes h_{s+1}
    int idv[2][4];
    #pragma unroll
    for (int m = 0; m < 2; ++m)
      #pragma unroll
      for (int reg = 0; reg < 4; ++reg){
        int len = lenr[m][reg];
        idv[m][reg] = (s < len) ? ids_s[(m*16 + q*4 + reg)*16 + (d ? (len-1-s) : s)] : -1;
      }
    #pragma unroll
    for (int ti = 0; ti < 2; ++ti){
      const int tau = wave*2 + ti;
      #pragma unroll
      for (int m = 0; m < 2; ++m){
        f32x4 acc[4];
        #pragma unroll
        for (int g = 0; g < 4; ++g)
          #pragma unroll
          for (int reg = 0; reg < 4; ++reg){
            int id = idv[m][reg];
            acc[g][reg] = (id >= 0) ? bf2f(tab[(size_t)id*512 + g*128 + tau*16 + l]) : 0.f;
          }
        #pragma unroll
        for (int kq = 0; kq < 4; ++kq)
          #pragma unroll
          for (int g = 0; g < 4; ++g)
            acc[g] = __builtin_amdgcn_mfma_f32_16x16x32_bf16(af[m][kq], wf[ti][g][kq], acc[g], 0, 0, 0);
        #pragma unroll
        for (int reg = 0; reg < 4; ++reg){
          float i_ = acc[0][reg], j_ = acc[1][reg], f_ = acc[2][reg], o_ = acc[3][reg];
          float cv = c_st[ti][m][reg];
          float cn = cv * sigm(f_ + 1.0f) + sigm(i_) * tanh_(j_);
          float hn = sigm(o_) * tanh_(cn);
          bool upd = s < lenr[m][reg];
          c_st[ti][m][reg] = upd ? cn : cv;
          int col = tau*16 + l;
          if (upd && col < 100) hbf[(m*16 + q*4 + reg)*136 + col] = f2bf(hn);
        }
      }
    }
    __syncthreads();
  }
  for (int i = tid; i < 3200; i += 256){
    int r = i / 100, c = i - r*100;
    A_w[(size_t)rows_s[r]*512 + 300 + d*100 + c] = hbf[r*136 + c];
  }
}

// ---------------- word-x GEMM: pre = A_w @ Bt^T + bias (128x128 tile) ----------------
__global__ __launch_bounds__(256,2) void k_gemm(const u16* __restrict__ Aw,
    const u16* __restrict__ Bt, const float* __restrict__ biasP, u16* __restrict__ pre)
{
  __shared__ __align__(16) u16 lA[128*40];
  __shared__ __align__(16) u16 lB[128*40];
  const int tid = threadIdx.x;
  const int m0 = blockIdx.x * 128, n0 = blockIdx.y * 128;
  const int wave = tid >> 6, lane = tid & 63, q = lane >> 4, l = lane & 15;
  const int wm = wave & 1, wn = wave >> 1;
  const f32x4 fz = {0.f, 0.f, 0.f, 0.f};
  f32x4 acc[4][4];
  #pragma unroll
  for (int i = 0; i < 4; ++i)
    #pragma unroll
    for (int j = 0; j < 4; ++j) acc[i][j] = fz;
  const int r0 = tid >> 2, off = (tid & 3)*8;
  for (int kk = 0; kk < 512; kk += 32){
    __syncthreads();
    #pragma unroll
    for (int r = 0; r < 2; ++r){
      int row = r*64 + r0;
      *(uint4*)&lA[row*40 + off] = *(const uint4*)&Aw[(size_t)(m0+row)*512 + kk + off];
      *(uint4*)&lB[row*40 + off] = *(const uint4*)&Bt[(size_t)(n0+row)*512 + kk + off];
    }
    __syncthreads();
    bf16x8 af[4], bf[4];
    #pragma unroll
    for (int i = 0; i < 4; ++i) af[i] = *(const bf16x8*)&lA[(wm*64 + i*16 + l)*40 + q*8];
    #pragma unroll
    for (int j = 0; j < 4; ++j) bf[j] = *(const bf16x8*)&lB[(wn*64 + j*16 + l)*40 + q*8];
    #pragma unroll
    for (int i = 0; i < 4; ++i)
      #pragma unroll
      for (int j = 0; j < 4; ++j)
        acc[i][j] = __builtin_amdgcn_mfma_f32_16x16x32_bf16(af[i], bf[j], acc[i][j], 0, 0, 0);
  }
  float bv[4];
  #pragma unroll
  for (int j = 0; j < 4; ++j) bv[j] = biasP[n0 + wn*64 + j*16 + l];
  #pragma unroll
  for (int i = 0; i < 4; ++i)
    #pragma unroll
    for (int j = 0; j < 4; ++j)
      #pragma unroll
      for (int reg = 0; reg < 4; ++reg){
        int row = m0 + wm*64 + i*16 + q*4 + reg;
        int col = n0 + wn*64 + j*16 + l;
        pre[(size_t)row*2432 + col] = f2bf(acc[i][j][reg] + bv[j]);
      }
}

// ---------------- word BiLSTM (R6): R2 protocol, pipelined sc1 VMEM for bulk data ----------------
// Theory (R4 post-mortem): __hip_atomic_* agent-scope ops serialize (~850cy IC
// RT each, no pipelining): R2 = 20 atomic h-loads/step = 7.1us/step; R4 = 40
// per poll = 16us/step. Fix: bulk h traffic uses plain global VMEM with the
// sc1 cache-policy bit (same L1/L2-bypass coherence as relaxed agent atomics)
// -> 10 loads in flight = ~1 RT. The 10 loads + trailing s_waitcnt vmcnt(0)
// live in ONE asm block (outputs can't be used before the asm completes; no
// tied operands -> compiles). Only per-wave flag store + 1-word poll load
// remain atomic. Protocol (parity dbuf, vmcnt-before-flag, re-store held h)
// identical to the R2 kernel that measured clean.
__global__ __launch_bounds__(256,1) void k_word(
    const int* __restrict__ slen, const u16* __restrict__ packW, const u16* __restrict__ pre,
    u16* __restrict__ hbuf, float* __restrict__ cfin, int* __restrict__ flags)
{
  const int b = blockIdx.x;
  const int g8 = b & 7;               // group: (d, batch-quarter)
  const int d = g8 & 1, grp = g8 >> 1;
  const int j = b >> 3;               // member 0..9, owns h-tiles {j, j+10}
  const int tid = threadIdx.x;
  const int wave = tid >> 6, lane = tid & 63, q = lane >> 4, l = lane & 15;
  const int tau = j + 10*(wave & 1);
  const int m = wave >> 1;
  __shared__ int slen_s[32];
  if (tid < 32) slen_s[tid] = slen[grp*32 + tid];
  bf16x8 wf[4][10];
  {
    const u16* pw = packW + ((size_t)(d*20 + tau))*4*10*512;
    #pragma unroll
    for (int gg = 0; gg < 4; ++gg)
      #pragma unroll
      for (int kq = 0; kq < 10; ++kq)
        wf[gg][kq] = *(const bf16x8*)&pw[((gg*10 + kq)*64 + lane)*8];
  }
  __syncthreads();
  int maxlen = 1;
  for (int i = 0; i < 32; ++i) maxlen = max(maxlen, slen_s[i]);
  int lenr[4];
  #pragma unroll
  for (int reg = 0; reg < 4; ++reg) lenr[reg] = slen_s[m*16 + q*4 + reg];
  float c_st[4] = {0.f, 0.f, 0.f, 0.f};
  u16  h_st[4] = {0, 0, 0, 0};
  int* gflags = flags + g8*64;
  int* myflag = gflags + (j*4 + wave);         // 40 waves per group
  int* pollp  = gflags + ((lane < 40) ? lane : 39);
  const int colz = tau*16 + l;
  const bool colok = colz < 300;
  const int rowb0 = grp*32 + m*16 + q*4;
  const size_t HB = (size_t)2*128*320;          // per-parity elements
  const u16* hb_rd0 = hbuf + ((size_t)(d*128 + grp*32 + m*16 + l))*320 + q*8;
  u16* hb_wr0 = hbuf + ((size_t)(d*128 + rowb0))*320 + colz;
  for (int s = 0; s < maxlen; ++s){
    // pre loads issued BEFORE the poll (independent of h; overlap HBM latency)
    u16 pu[4][4];
    #pragma unroll
    for (int gg = 0; gg < 4; ++gg)
      #pragma unroll
      for (int reg = 0; reg < 4; ++reg){
        int len = lenr[reg];
        bool ok = (s < len) && colok;
        int t = d ? (len-1-s) : s;
        pu[gg][reg] = ok ? pre[((size_t)((rowb0+reg)*256 + t))*2432 + d*1200 + gg*300 + colz] : (u16)0;
      }
    if (s > 0){
      int guard = 0;
      for (;;){
        int v = __hip_atomic_load(pollp, __ATOMIC_RELAXED, __HIP_MEMORY_SCOPE_AGENT);
        unsigned long long ok = __ballot(v >= s);
        if ((ok & 0xFFFFFFFFFFull) == 0xFFFFFFFFFFull) break;
        if (++guard > 8192) break;    // bounded: bug -> wrong answer, not hang
      }
      asm volatile("" ::: "memory");
    }
    uint4 r[10];
    if (s == 0){
      const uint4 z = {0u, 0u, 0u, 0u};
      #pragma unroll
      for (int i = 0; i < 10; ++i) r[i] = z;   // h_0 = 0, no fetch needed
    } else {
      const u16* hb = hb_rd0 + (size_t)(s & 1)*HB;
      // 10 pipelined sc1 loads + drain, one asm block: outputs unusable
      // before the internal vmcnt(0) -> correctness enforced by dataflow.
      asm volatile(
        "global_load_dwordx4 %0, %10, off sc1\n\t"
        "global_load_dwordx4 %1, %10, off offset:64 sc1\n\t"
        "global_load_dwordx4 %2, %10, off offset:128 sc1\n\t"
        "global_load_dwordx4 %3, %10, off offset:192 sc1\n\t"
        "global_load_dwordx4 %4, %10, off offset:256 sc1\n\t"
        "global_load_dwordx4 %5, %10, off offset:320 sc1\n\t"
        "global_load_dwordx4 %6, %10, off offset:384 sc1\n\t"
        "global_load_dwordx4 %7, %10, off offset:448 sc1\n\t"
        "global_load_dwordx4 %8, %10, off offset:512 sc1\n\t"
        "global_load_dwordx4 %9, %10, off offset:576 sc1\n\t"
        "s_waitcnt vmcnt(0)"
        : "=v"(r[0]), "=v"(r[1]), "=v"(r[2]), "=v"(r[3]), "=v"(r[4]),
          "=v"(r[5]), "=v"(r[6]), "=v"(r[7]), "=v"(r[8]), "=v"(r[9])
        : "v"(hb)
        : "memory");
    }
    bf16x8 af[10];
    #pragma unroll
    for (int kq = 0; kq < 10; ++kq){
      union { uint4 u; bf16x8 v; } t; t.u = r[kq];
      af[kq] = t.v;
    }
    f32x4 acc[4];
    #pragma unroll
    for (int gg = 0; gg < 4; ++gg)
      #pragma unroll
      for (int reg = 0; reg < 4; ++reg) acc[gg][reg] = bf2f(pu[gg][reg]);
    #pragma unroll
    for (int kq = 0; kq < 10; ++kq)
      #pragma unroll
      for (int gg = 0; gg < 4; ++gg)
        acc[gg] = __builtin_amdgcn_mfma_f32_16x16x32_bf16(af[kq], wf[gg][kq], acc[gg], 0, 0, 0);
    #pragma unroll
    for (int reg = 0; reg < 4; ++reg){
      float i_ = acc[0][reg], j_ = acc[1][reg], f_ = acc[2][reg], o_ = acc[3][reg];
      float cv = c_st[reg];
      float cn = cv * sigm(f_ + 1.0f) + sigm(i_) * tanh_(j_);
      float hn = sigm(o_) * tanh_(cn);
      bool upd = s < lenr[reg];
      c_st[reg] = upd ? cn : cv;
      h_st[reg] = upd ? f2bf(hn) : h_st[reg];
    }
    // publish h_{s+1} (re-store held h for masked rows) via plain sc1 stores
    u16* hw = hb_wr0 + (size_t)((s+1) & 1)*HB;
    if (colok){
      #pragma unroll
      for (int reg = 0; reg < 4; ++reg){
        u32 val = (u32)h_st[reg];
        asm volatile("global_store_short %0, %1, off sc1"
                     :: "v"(hw + reg*320), "v"(val) : "memory");
      }
    }
    asm volatile("s_waitcnt vmcnt(0)" ::: "memory");   // stores at IC before flag
    if (lane == 0)
      __hip_atomic_store(myflag, s + 1, __ATOMIC_RELAXED, __HIP_MEMORY_SCOPE_AGENT);
  }
  #pragma unroll
  for (int reg = 0; reg < 4; ++reg)
    if (colok) cfin[((size_t)(d*128 + rowb0 + reg))*300 + colz] = c_st[reg];
}

// ---------------- final projection + log-softmax NLL ----------------
__global__ void k_final(const float* __restrict__ cfin, const float* __restrict__ Wp,
                        const float* __restrict__ bp, const int* __restrict__ labels,
                        float* __restrict__ out)
{
  __shared__ float lg[384];
  __shared__ float red[128];
  int tid = threadIdx.x;
  for (int t = tid; t < 384; t += 256){
    int bb = t / 3, k = t - bb*3;
    float s = bp[k];
    for (int n = 0; n < 600; ++n){
      float v = (n < 300) ? cfin[bb*300 + n] : cfin[(128 + bb)*300 + (n - 300)];
      s += v * Wp[n*3 + k];
    }
    lg[bb*3 + k] = s;
  }
  __syncthreads();
  if (tid < 128){
    float a = lg[tid*3], b2 = lg[tid*3+1], c = lg[tid*3+2];
    float mx = fmaxf(a, fmaxf(b2, c));
    float lse = mx + __logf(__expf(a-mx) + __expf(b2-mx) + __expf(c-mx));
    red[tid] = lg[tid*3 + labels[tid]] - lse;
  }
  __syncthreads();
  for (int off = 64; off > 0; off >>= 1){
    if (tid < off) red[tid] += red[tid + off];
    __syncthreads();
  }
  if (tid == 0) out[0] = -red[0] / 128.f;
}

// ---------------- launch ----------------
extern "C" void kernel_launch(void* const* d_in, const int* in_sizes, int n_in,
                              void* d_out, int out_size, void* d_ws, size_t ws_size,
                              hipStream_t stream)
{
  const int*   wid    = (const int*)d_in[0];
  const int*   slen   = (const int*)d_in[1];
  const int*   cids   = (const int*)d_in[2];
  const int*   wlen   = (const int*)d_in[3];
  const int*   labels = (const int*)d_in[4];
  const float* wemb   = (const float*)d_in[5];
  const float* cemb   = (const float*)d_in[6];
  const float* Wc_fw  = (const float*)d_in[7];
  const float* bc_fw  = (const float*)d_in[8];
  const float* Wc_bw  = (const float*)d_in[9];
  const float* bc_bw  = (const float*)d_in[10];
  const float* Ww_fw  = (const float*)d_in[11];
  const float* bw_fw  = (const float*)d_in[12];
  const float* Ww_bw  = (const float*)d_in[13];
  const float* bw_bw  = (const float*)d_in[14];
  const float* Wp     = (const float*)d_in[15];
  const float* bp     = (const float*)d_in[16];

  char* ws = (char*)d_ws;
  u16*   tableC = (u16*)(ws + OFF_TABLE);
  u16*   packC  = (u16*)(ws + OFF_PACKC);
  u16*   packW  = (u16*)(ws + OFF_PACKW);
  u16*   Bt     = (u16*)(ws + OFF_BT);
  float* biasP  = (float*)(ws + OFF_BIAS);
  u16*   A_w    = (u16*)(ws + OFF_AW);
  u16*   pre    = (u16*)(ws + OFF_PRE);
  u16*   hbuf   = (u16*)(ws + OFF_HBUF);
  float* cfin   = (float*)(ws + OFF_CFIN);
  int*   ridx   = (int*)(ws + OFF_RIDX);
  int*   flags  = (int*)(ws + OFF_CNT);

  (void)hipMemsetAsync(ws + OFF_HBUF, 0, SZ_HBUF, stream);   // h0 = 0 (both parities)
  (void)hipMemsetAsync(ws + OFF_CNT,  0, SZ_CNT,  stream);   // per-wave flags

  k_table <<<dim3(202),  dim3(256), 0, stream>>>(cemb, Wc_fw, bc_fw, Wc_bw, bc_bw, tableC);
  k_packC <<<dim3(512),  dim3(256), 0, stream>>>(Wc_fw, Wc_bw, packC);
  k_packW <<<dim3(3200), dim3(256), 0, stream>>>(Ww_fw, Ww_bw, packW);
  k_packBt<<<dim3(4864), dim3(256), 0, stream>>>(Ww_fw, bw_fw, Ww_bw, bw_bw, Bt, biasP);
  k_sortC <<<dim3(1),    dim3(256), 0, stream>>>(wlen, ridx);
  k_embed <<<dim3(8192), dim3(256), 0, stream>>>(wid, wemb, A_w);
  k_char  <<<dim3(2048), dim3(256), 0, stream>>>(ridx, wlen, cids, tableC, packC, A_w);
  k_gemm  <<<dim3(256, 19), dim3(256), 0, stream>>>(A_w, Bt, biasP, pre);
  k_word  <<<dim3(80),   dim3(256), 0, stream>>>(slen, packW, pre, hbuf, cfin, flags);
  k_final <<<dim3(1),    dim3(256), 0, stream>>>(cfin, Wp, bp, labels, (float*)d_out);
}